// Round 5
// baseline (53.039 us; speedup 1.0000x reference)
//
#include <hip/hip_runtime.h>

#define EPS 1e-10f
#define FAR_DELTA 1e10f

// clang native vector type: __builtin_nontemporal_load requires it
// (HIP's float4 is a struct and is rejected).
typedef float vf4 __attribute__((ext_vector_type(4)));

// 4 rays per wave: each 16-lane segment owns one ray, 8 samples per lane.
// S = 128, C = 3 hard-coded (matches setup_inputs()).
__global__ __launch_bounds__(256) void volrender_kernel(
    const float* __restrict__ density,   // [N,128]
    const float* __restrict__ feature,   // [N,128,3]
    const float* __restrict__ depth,     // [N,128]
    float* __restrict__ out,             // [N,4]
    int N)
{
    const int wave = (blockIdx.x * blockDim.x + threadIdx.x) >> 6;
    const int lane = threadIdx.x & 63;
    const int sub  = lane & 15;          // lane within the ray's 16-lane segment
    const int rloc = lane >> 4;          // which of the wave's 4 rays
    int n = wave * 4 + rloc;
    const bool valid = (n < N);
    if (!valid) n = 0;                   // harmless loads; store is guarded

    const float* dp = depth   + (size_t)n * 128 + sub * 8;
    const float* sp = density + (size_t)n * 128 + sub * 8;
    const float* fp = feature + (size_t)n * 384 + sub * 24;

    // ---- coalesced float4 non-temporal loads (16B/lane, no reuse -> nt) ----
    const vf4 d0 = __builtin_nontemporal_load((const vf4*)(dp));
    const vf4 d1 = __builtin_nontemporal_load((const vf4*)(dp + 4));
    const vf4 s0 = __builtin_nontemporal_load((const vf4*)(sp));
    const vf4 s1 = __builtin_nontemporal_load((const vf4*)(sp + 4));
    const vf4 fA = __builtin_nontemporal_load((const vf4*)(fp));
    const vf4 fB = __builtin_nontemporal_load((const vf4*)(fp + 4));
    const vf4 fC = __builtin_nontemporal_load((const vf4*)(fp + 8));
    const vf4 fD = __builtin_nontemporal_load((const vf4*)(fp + 12));
    const vf4 fE = __builtin_nontemporal_load((const vf4*)(fp + 16));
    const vf4 fF = __builtin_nontemporal_load((const vf4*)(fp + 20));

    float d[8] = {d0.x, d0.y, d0.z, d0.w, d1.x, d1.y, d1.z, d1.w};
    float s[8] = {s0.x, s0.y, s0.z, s0.w, s1.x, s1.y, s1.z, s1.w};
    const float f[8][3] = {
        {fA.x, fA.y, fA.z}, {fA.w, fB.x, fB.y},
        {fB.z, fB.w, fC.x}, {fC.y, fC.z, fC.w},
        {fD.x, fD.y, fD.z}, {fD.w, fE.x, fE.y},
        {fE.z, fE.w, fF.x}, {fF.y, fF.z, fF.w}};

    // ---- deltas & exponents ----
    const float dnext = __shfl_down(d[0], 1, 64);  // next lane's first depth
    float e[8];
    #pragma unroll
    for (int j = 0; j < 7; ++j) e[j] = s[j] * (d[j + 1] - d[j]);
    e[7] = s[7] * ((sub == 15) ? FAR_DELTA : (dnext - d[7]));

    // Global last sample's exponent (density*1e10) must NOT enter the scan:
    // fp32 ulp(1e10)=1024 would annihilate the finite prefix.
    const float local = e[0] + e[1] + e[2] + e[3] + e[4] + e[5] + e[6]
                      + ((sub == 15) ? 0.0f : e[7]);

    // ---- segmented (width=16) inclusive scan ----
    float x = local;
    #pragma unroll
    for (int off = 1; off < 16; off <<= 1) {
        const float y = __shfl_up(x, off, 16);
        if (sub >= off) x += y;
    }
    float excl = __shfl_up(x, 1, 16);
    if (sub == 0) excl = 0.0f;

    // ---- transmittances: w_j = T_j - T_{j+1}  (halves the exp count;
    //      differs from reference by a factor exp(EPS) ~ 1+1e-10) ----
    float cc[9];
    cc[0] = excl;
    float p = 0.0f;
    #pragma unroll
    for (int j = 1; j < 9; ++j) { p += e[j - 1]; cc[j] = excl + p; }
    // For the global last sample, cc[8] includes density*1e10 -> T[8] = 0 -> w = T[7] (alpha ~ 1).
    float T[9];
    #pragma unroll
    for (int j = 0; j < 9; ++j) T[j] = expf(EPS - cc[j]);

    float o0 = 0.f, o1 = 0.f, o2 = 0.f, o3 = 0.f;
    #pragma unroll
    for (int j = 0; j < 8; ++j) {
        const float w = T[j] - T[j + 1];
        o0 += w * f[j][0];
        o1 += w * f[j][1];
        o2 += w * f[j][2];
        o3 += w * d[j];
    }

    // ---- segmented (width=16) butterfly reduction ----
    #pragma unroll
    for (int off = 1; off < 16; off <<= 1) {
        o0 += __shfl_xor(o0, off, 16);
        o1 += __shfl_xor(o1, off, 16);
        o2 += __shfl_xor(o2, off, 16);
        o3 += __shfl_xor(o3, off, 16);
    }

    if (sub == 0 && valid) {
        *(float4*)(out + (size_t)n * 4) = make_float4(o0, o1, o2, o3);
    }
}

extern "C" void kernel_launch(void* const* d_in, const int* in_sizes, int n_in,
                              void* d_out, int out_size, void* d_ws, size_t ws_size,
                              hipStream_t stream) {
    const float* density = (const float*)d_in[0];   // [N,128]
    const float* feature = (const float*)d_in[1];   // [N,128,3]
    const float* depth   = (const float*)d_in[2];   // [N,128]
    float* out = (float*)d_out;                     // [N,4]

    const int N = in_sizes[0] / 128;
    const int threads = 256;                 // 4 waves/block, 4 rays/wave
    const int blocks = (N + 15) / 16;        // 16 rays/block
    volrender_kernel<<<blocks, threads, 0, stream>>>(density, feature, depth, out, N);
}

// Round 6
// 28.957 us; speedup vs baseline: 1.8316x; 1.8316x over previous
//
#include <hip/hip_runtime.h>

#define EPS 1e-10f
#define FAR_DELTA 1e10f

typedef float vf4 __attribute__((ext_vector_type(4)));

// 4 rays per wave: each 16-lane segment owns one ray, 8 samples per lane.
// S = 128, C = 3 hard-coded (matches setup_inputs()).
// NOTE: plain (cached) loads — nontemporal loads regressed 30->53us by
// evicting the L3-resident input set (R4 experiment).
__global__ __launch_bounds__(256) void volrender_kernel(
    const float* __restrict__ density,   // [N,128]
    const float* __restrict__ feature,   // [N,128,3]
    const float* __restrict__ depth,     // [N,128]
    float* __restrict__ out,             // [N,4]
    int N)
{
    const int wave = (blockIdx.x * blockDim.x + threadIdx.x) >> 6;
    const int lane = threadIdx.x & 63;
    const int sub  = lane & 15;          // lane within the ray's 16-lane segment
    const int rloc = lane >> 4;          // which of the wave's 4 rays
    int n = wave * 4 + rloc;
    const bool valid = (n < N);
    if (!valid) n = 0;                   // harmless loads; store is guarded

    const float* dp = depth   + (size_t)n * 128 + sub * 8;
    const float* sp = density + (size_t)n * 128 + sub * 8;
    const float* fp = feature + (size_t)n * 384 + sub * 24;

    // ---- coalesced float4 loads (16B/lane) ----
    const vf4 d0 = *(const vf4*)(dp);
    const vf4 d1 = *(const vf4*)(dp + 4);
    const vf4 s0 = *(const vf4*)(sp);
    const vf4 s1 = *(const vf4*)(sp + 4);
    const vf4 fA = *(const vf4*)(fp);
    const vf4 fB = *(const vf4*)(fp + 4);
    const vf4 fC = *(const vf4*)(fp + 8);
    const vf4 fD = *(const vf4*)(fp + 12);
    const vf4 fE = *(const vf4*)(fp + 16);
    const vf4 fF = *(const vf4*)(fp + 20);

    float d[8] = {d0.x, d0.y, d0.z, d0.w, d1.x, d1.y, d1.z, d1.w};
    float s[8] = {s0.x, s0.y, s0.z, s0.w, s1.x, s1.y, s1.z, s1.w};
    const float f[8][3] = {
        {fA.x, fA.y, fA.z}, {fA.w, fB.x, fB.y},
        {fB.z, fB.w, fC.x}, {fC.y, fC.z, fC.w},
        {fD.x, fD.y, fD.z}, {fD.w, fE.x, fE.y},
        {fE.z, fE.w, fF.x}, {fF.y, fF.z, fF.w}};

    // ---- deltas & exponents ----
    const float dnext = __shfl_down(d[0], 1, 64);  // next lane's first depth
    float e[8];
    #pragma unroll
    for (int j = 0; j < 7; ++j) e[j] = s[j] * (d[j + 1] - d[j]);
    e[7] = s[7] * ((sub == 15) ? FAR_DELTA : (dnext - d[7]));

    // Global last sample's exponent (density*1e10) must NOT enter the scan:
    // fp32 ulp(1e10)=1024 would annihilate the finite prefix.
    const float local = e[0] + e[1] + e[2] + e[3] + e[4] + e[5] + e[6]
                      + ((sub == 15) ? 0.0f : e[7]);

    // ---- segmented (width=16) inclusive scan ----
    float x = local;
    #pragma unroll
    for (int off = 1; off < 16; off <<= 1) {
        const float y = __shfl_up(x, off, 16);
        if (sub >= off) x += y;
    }
    float excl = __shfl_up(x, 1, 16);
    if (sub == 0) excl = 0.0f;

    // ---- transmittances: w_j = T_j - T_{j+1}  (halves the exp count;
    //      differs from reference by a factor exp(EPS) ~ 1+1e-10) ----
    float cc[9];
    cc[0] = excl;
    float p = 0.0f;
    #pragma unroll
    for (int j = 1; j < 9; ++j) { p += e[j - 1]; cc[j] = excl + p; }
    // For the global last sample, cc[8] includes density*1e10 -> T[8] = 0 -> w = T[7] (alpha ~ 1).
    float T[9];
    #pragma unroll
    for (int j = 0; j < 9; ++j) T[j] = expf(EPS - cc[j]);

    float o0 = 0.f, o1 = 0.f, o2 = 0.f, o3 = 0.f;
    #pragma unroll
    for (int j = 0; j < 8; ++j) {
        const float w = T[j] - T[j + 1];
        o0 += w * f[j][0];
        o1 += w * f[j][1];
        o2 += w * f[j][2];
        o3 += w * d[j];
    }

    // ---- segmented (width=16) butterfly reduction ----
    #pragma unroll
    for (int off = 1; off < 16; off <<= 1) {
        o0 += __shfl_xor(o0, off, 16);
        o1 += __shfl_xor(o1, off, 16);
        o2 += __shfl_xor(o2, off, 16);
        o3 += __shfl_xor(o3, off, 16);
    }

    if (sub == 0 && valid) {
        *(float4*)(out + (size_t)n * 4) = make_float4(o0, o1, o2, o3);
    }
}

extern "C" void kernel_launch(void* const* d_in, const int* in_sizes, int n_in,
                              void* d_out, int out_size, void* d_ws, size_t ws_size,
                              hipStream_t stream) {
    const float* density = (const float*)d_in[0];   // [N,128]
    const float* feature = (const float*)d_in[1];   // [N,128,3]
    const float* depth   = (const float*)d_in[2];   // [N,128]
    float* out = (float*)d_out;                     // [N,4]

    const int N = in_sizes[0] / 128;
    const int threads = 256;                 // 4 waves/block, 4 rays/wave
    const int blocks = (N + 15) / 16;        // 16 rays/block
    volrender_kernel<<<blocks, threads, 0, stream>>>(density, feature, depth, out, N);
}